// Round 1
// baseline (218.623 us; speedup 1.0000x reference)
//
#include <hip/hip_runtime.h>

// Problem constants
#define B_TOT 8192
#define O_DIM 512
#define L_DIM 128
#define K_DIM 8
#define H_DIM 20

// Tiling
#define TO 16          // o per block
#define TB 32          // b per block
#define RB 2           // b per thread
#define NTH 256        // threads per block
#define WREC 644       // floats per o-record in LDS (641 padded to mult of 4)
#define XROW 132       // x row stride in LDS (128 + 4 pad: breaks bank aliasing, keeps 16B align)

// tanh(x) = 1 - 2/(1+exp(2x)); exp via hw exp2, division via hw rcp.
// x->+inf: e=inf, rcp=0 -> 1.  x->-inf: e=0 -> -1.  Correct saturation.
__device__ __forceinline__ float fast_tanh(float x) {
    float e = __builtin_amdgcn_exp2f(x * 2.885390081777927f); // 2*log2(e)
    float r = __builtin_amdgcn_rcpf(1.0f + e);
    return 1.0f - 2.0f * r;
}

// Load 20 consecutive floats from 16B-aligned LDS as 5x ds_read_b128.
__device__ __forceinline__ void load20(const float* p, float* v) {
    const float4* p4 = (const float4*)p;
    float4 a = p4[0], b = p4[1], c = p4[2], d = p4[3], e = p4[4];
    v[0]=a.x;  v[1]=a.y;  v[2]=a.z;  v[3]=a.w;
    v[4]=b.x;  v[5]=b.y;  v[6]=b.z;  v[7]=b.w;
    v[8]=c.x;  v[9]=c.y;  v[10]=c.z; v[11]=c.w;
    v[12]=d.x; v[13]=d.y; v[14]=d.z; v[15]=d.w;
    v[16]=e.x; v[17]=e.y; v[18]=e.z; v[19]=e.w;
}

__global__ __launch_bounds__(NTH, 2) void medil_fused(
    const float* __restrict__ x, const float* __restrict__ noise,
    const int* __restrict__ cause_idx,
    const float* __restrict__ W1, const float* __restrict__ b1,
    const float* __restrict__ W2, const float* __restrict__ b2,
    const float* __restrict__ W3, const float* __restrict__ b3,
    float* __restrict__ out)
{
    // Per-o record layout (floats): W1[9][20] @0, b1[20] @180, W2[20][20] @200,
    // b2[20] @600, W3[20] @620, b3 @640.  All row offsets are 16B-multiples.
    __shared__ __align__(16) float w_lds[TO * WREC];   // 41216 B
    __shared__ __align__(16) float x_lds[TB * XROW];   // 16896 B
    __shared__ int idx_lds[TO * K_DIM];                //   512 B  -> 58.6 KB total

    const int tid = threadIdx.x;
    const int nob = O_DIM / TO;                        // 32 o-blocks
    const int o0 = (blockIdx.x % nob) * TO;
    const int b0 = (blockIdx.x / nob) * TB;

    // ---- stage the 16 W records: 16 threads cooperate per o ----
    {
        const int og = tid >> 4;       // which o_local this group stages
        const int j0 = tid & 15;
        const int o  = o0 + og;
        float* rec = w_lds + og * WREC;
        const float* w1p = W1 + (size_t)o * 180;
        for (int j = j0; j < 180; j += 16) rec[j] = w1p[j];
        const float* w2p = W2 + (size_t)o * 400;
        for (int j = j0; j < 400; j += 16) rec[200 + j] = w2p[j];
        for (int j = j0; j < 20; j += 16) rec[180 + j] = b1[o * H_DIM + j];
        for (int j = j0; j < 20; j += 16) rec[600 + j] = b2[o * H_DIM + j];
        for (int j = j0; j < 20; j += 16) rec[620 + j] = W3[o * H_DIM + j];
        if (j0 == 0) rec[640] = b3[o];
    }
    // ---- stage indices (128 ints, flat) ----
    if (tid < TO * K_DIM) idx_lds[tid] = cause_idx[o0 * K_DIM + tid];
    // ---- stage x tile: 32 rows x 32 float4, fully coalesced ----
    {
        const float4* xg = (const float4*)(x + (size_t)b0 * L_DIM);
        for (int c = tid; c < TB * (L_DIM / 4); c += NTH) {
            int row = c >> 5, col = c & 31;
            *(float4*)(x_lds + row * XROW + col * 4) = xg[row * 32 + col];
        }
    }
    __syncthreads();

    // thread -> (o_local, 2 consecutive local b's)
    const int ol = tid & 15;            // lanes 0..15 = consecutive o -> coalesced noise/out
    const int bl = (tid >> 4) * RB;
    const float* rec = w_lds + ol * WREC;

    // ---- inputs: inp[r][0]=noise, inp[r][1+k]=x gather ----
    float inp[RB][K_DIM + 1];
    #pragma unroll
    for (int r = 0; r < RB; ++r)
        inp[r][0] = noise[(size_t)(b0 + bl + r) * O_DIM + o0 + ol];
    #pragma unroll
    for (int k = 0; k < K_DIM; ++k) {
        int col = idx_lds[ol * K_DIM + k];
        #pragma unroll
        for (int r = 0; r < RB; ++r)
            inp[r][k + 1] = x_lds[(bl + r) * XROW + col];
    }

    // ---- layer 1: h1 = tanh(inp @ W1 + b1) ----
    float h1[RB][H_DIM];
    {
        float bb[H_DIM]; load20(rec + 180, bb);
        #pragma unroll
        for (int h = 0; h < H_DIM; ++h)
            #pragma unroll
            for (int r = 0; r < RB; ++r) h1[r][h] = bb[h];
        #pragma unroll
        for (int i = 0; i < K_DIM + 1; ++i) {
            float w[H_DIM]; load20(rec + i * H_DIM, w);
            #pragma unroll
            for (int h = 0; h < H_DIM; ++h)
                #pragma unroll
                for (int r = 0; r < RB; ++r)
                    h1[r][h] = fmaf(inp[r][i], w[h], h1[r][h]);
        }
        #pragma unroll
        for (int h = 0; h < H_DIM; ++h)
            #pragma unroll
            for (int r = 0; r < RB; ++r) h1[r][h] = fast_tanh(h1[r][h]);
    }

    // ---- layer 2: h2 = tanh(h1 @ W2 + b2) ----
    float h2[RB][H_DIM];
    {
        float bb[H_DIM]; load20(rec + 600, bb);
        #pragma unroll
        for (int g = 0; g < H_DIM; ++g)
            #pragma unroll
            for (int r = 0; r < RB; ++r) h2[r][g] = bb[g];
        #pragma unroll
        for (int h = 0; h < H_DIM; ++h) {
            float w[H_DIM]; load20(rec + 200 + h * H_DIM, w);
            #pragma unroll
            for (int g = 0; g < H_DIM; ++g)
                #pragma unroll
                for (int r = 0; r < RB; ++r)
                    h2[r][g] = fmaf(h1[r][h], w[g], h2[r][g]);
        }
        #pragma unroll
        for (int g = 0; g < H_DIM; ++g)
            #pragma unroll
            for (int r = 0; r < RB; ++r) h2[r][g] = fast_tanh(h2[r][g]);
    }

    // ---- layer 3: out = h2 @ W3 + b3 ----
    {
        float w[H_DIM]; load20(rec + 620, w);
        float acc[RB];
        #pragma unroll
        for (int r = 0; r < RB; ++r) acc[r] = rec[640];
        #pragma unroll
        for (int h = 0; h < H_DIM; ++h)
            #pragma unroll
            for (int r = 0; r < RB; ++r)
                acc[r] = fmaf(h2[r][h], w[h], acc[r]);
        #pragma unroll
        for (int r = 0; r < RB; ++r)
            out[(size_t)(b0 + bl + r) * O_DIM + o0 + ol] = acc[r];
    }
}

extern "C" void kernel_launch(void* const* d_in, const int* in_sizes, int n_in,
                              void* d_out, int out_size, void* d_ws, size_t ws_size,
                              hipStream_t stream) {
    const float* x         = (const float*)d_in[0];
    const float* noise     = (const float*)d_in[1];
    const int*   cause_idx = (const int*)d_in[2];
    const float* W1        = (const float*)d_in[3];
    const float* b1        = (const float*)d_in[4];
    const float* W2        = (const float*)d_in[5];
    const float* b2        = (const float*)d_in[6];
    const float* W3        = (const float*)d_in[7];
    const float* b3        = (const float*)d_in[8];
    float* out = (float*)d_out;

    dim3 grid((B_TOT / TB) * (O_DIM / TO));  // 256 * 32 = 8192 blocks
    dim3 block(NTH);
    hipLaunchKernelGGL(medil_fused, grid, block, 0, stream,
                       x, noise, cause_idx, W1, b1, W2, b2, W3, b3, out);
}

// Round 2
// 192.277 us; speedup vs baseline: 1.1370x; 1.1370x over previous
//
#include <hip/hip_runtime.h>

// Problem: B=8192, L=128, O=512, K=8, H=20
#define B_TOT 8192
#define O_DIM 512
#define L_DIM 128
#define K_DIM 8
#define H_DIM 20

// Tiling: one o per wave, 64 b per wave (lane = b).
#define TB 64          // b per block (= wavefront)
#define G  16          // o per block (4 waves x 4 iterations)
#define NW 4           // waves per block
#define NTH 256
#define XSTR 65        // xT stride: transposed [col][b]; odd => gather conflict-free
#define NSTR 17        // noise tile stride: odd => read conflict-free

// tanh(x) = 1 - 2/(1+exp(2x)); saturates correctly at +/-inf.
__device__ __forceinline__ float fast_tanh(float x) {
    float e = __builtin_amdgcn_exp2f(x * 2.885390081777927f); // 2*log2(e)
    float r = __builtin_amdgcn_rcpf(1.0f + e);
    return 1.0f - 2.0f * r;
}

__global__ __launch_bounds__(NTH, 4) void medil_fused(
    const float* __restrict__ x, const float* __restrict__ noise,
    const int* __restrict__ cause_idx,
    const float* __restrict__ W1, const float* __restrict__ b1,
    const float* __restrict__ W2, const float* __restrict__ b2,
    const float* __restrict__ W3, const float* __restrict__ b3,
    float* __restrict__ out)
{
    __shared__ float xT[L_DIM * XSTR];   // 33280 B, transposed x tile [col][b]
    __shared__ float nt[TB * NSTR];      //  4352 B, noise tile [b][ol]
    // total 37.6 KB -> 4 blocks/CU -> 16 waves/CU

    const int tid = threadIdx.x;
    const int o0 = (blockIdx.x & 31) * G;        // 512/16 = 32 o-groups
    const int b0 = (blockIdx.x >> 5) * TB;       // 8192/64 = 128 b-tiles

    // ---- stage x tile transposed: xT[col][b_local] ----
    {
        const float4* xg = (const float4*)(x + (size_t)b0 * L_DIM);
        #pragma unroll
        for (int i = 0; i < 8; ++i) {
            int idx = tid + NTH * i;             // 0..2047
            int r = idx >> 5, c4 = idx & 31;     // row, col4 (coalesced global)
            float4 v = xg[r * 32 + c4];
            xT[(c4 * 4 + 0) * XSTR + r] = v.x;
            xT[(c4 * 4 + 1) * XSTR + r] = v.y;
            xT[(c4 * 4 + 2) * XSTR + r] = v.z;
            xT[(c4 * 4 + 3) * XSTR + r] = v.w;
        }
    }
    // ---- stage noise tile [64 b][16 o], coalesced float4 loads ----
    {
        int r = tid >> 2, c4 = tid & 3;
        float4 v = *(const float4*)(noise + (size_t)(b0 + r) * O_DIM + o0 + c4 * 4);
        nt[r * NSTR + c4 * 4 + 0] = v.x;
        nt[r * NSTR + c4 * 4 + 1] = v.y;
        nt[r * NSTR + c4 * 4 + 2] = v.z;
        nt[r * NSTR + c4 * 4 + 3] = v.w;
    }
    __syncthreads();

    const int lane = tid & 63;   // = b_local
    const int wv = tid >> 6;

    #pragma unroll
    for (int it = 0; it < G / NW; ++it) {
        // wave-uniform o => all W/b/idx accesses become scalar loads
        const int ol = __builtin_amdgcn_readfirstlane(wv * (G / NW) + it);
        const int o  = o0 + ol;

        const float* w1p = W1 + (size_t)o * (K_DIM + 1) * H_DIM;
        const float* b1p = b1 + (size_t)o * H_DIM;
        const float* w2p = W2 + (size_t)o * H_DIM * H_DIM;
        const float* b2p = b2 + (size_t)o * H_DIM;
        const float* w3p = W3 + (size_t)o * H_DIM;
        const int*   cip = cause_idx + (size_t)o * K_DIM;

        // gather: col wave-uniform, lanes consecutive -> conflict-free LDS
        float xi[K_DIM];
        #pragma unroll
        for (int k = 0; k < K_DIM; ++k)
            xi[k] = xT[cip[k] * XSTR + lane];
        float inp0 = nt[lane * NSTR + ol];

        // ---- layer 1: a1 = tanh(inp @ W1 + b1), W1 from SGPRs ----
        float a1[H_DIM];
        #pragma unroll
        for (int h = 0; h < H_DIM; ++h)
            a1[h] = fmaf(inp0, w1p[h], b1p[h]);
        #pragma unroll
        for (int k = 0; k < K_DIM; ++k)
            #pragma unroll
            for (int h = 0; h < H_DIM; ++h)
                a1[h] = fmaf(xi[k], w1p[(k + 1) * H_DIM + h], a1[h]);
        #pragma unroll
        for (int h = 0; h < H_DIM; ++h) a1[h] = fast_tanh(a1[h]);

        // ---- layer 2: a2 = tanh(a1 @ W2 + b2) ----
        float a2[H_DIM];
        #pragma unroll
        for (int g = 0; g < H_DIM; ++g) a2[g] = b2p[g];
        #pragma unroll
        for (int h = 0; h < H_DIM; ++h)
            #pragma unroll
            for (int g = 0; g < H_DIM; ++g)
                a2[g] = fmaf(a1[h], w2p[h * H_DIM + g], a2[g]);
        #pragma unroll
        for (int g = 0; g < H_DIM; ++g) a2[g] = fast_tanh(a2[g]);

        // ---- layer 3 + store (scatter; L2 merges: block covers full 64B o-line) ----
        float r = b3[o];
        #pragma unroll
        for (int h = 0; h < H_DIM; ++h) r = fmaf(a2[h], w3p[h], r);
        out[(size_t)(b0 + lane) * O_DIM + o] = r;
    }
}

extern "C" void kernel_launch(void* const* d_in, const int* in_sizes, int n_in,
                              void* d_out, int out_size, void* d_ws, size_t ws_size,
                              hipStream_t stream) {
    const float* x         = (const float*)d_in[0];
    const float* noise     = (const float*)d_in[1];
    const int*   cause_idx = (const int*)d_in[2];
    const float* W1        = (const float*)d_in[3];
    const float* b1        = (const float*)d_in[4];
    const float* W2        = (const float*)d_in[5];
    const float* b2        = (const float*)d_in[6];
    const float* W3        = (const float*)d_in[7];
    const float* b3        = (const float*)d_in[8];
    float* out = (float*)d_out;

    dim3 grid((B_TOT / TB) * (O_DIM / G));   // 128 * 32 = 4096 blocks
    dim3 block(NTH);
    hipLaunchKernelGGL(medil_fused, grid, block, 0, stream,
                       x, noise, cause_idx, W1, b1, W2, b2, W3, b3, out);
}